// Round 18
// baseline (155.171 us; speedup 1.0000x reference)
//
#include <hip/hip_runtime.h>
#include <hip/hip_bf16.h>

// Problem constants
#define B_   128
#define J_   2048
#define N_   32
#define D_   16
#define NJC  64       // j-chunks (32 j each) for capsA s-partials

typedef __attribute__((ext_vector_type(8))) short short8b;   // 8 bf16 (4 VGPRs)
typedef __attribute__((ext_vector_type(4))) float f32x4;     // 16x16 MFMA acc
typedef __attribute__((ext_vector_type(16))) float f32x16;   // 32x32 MFMA acc

__device__ inline short bf16s(float f) {
    union { __hip_bfloat16 h; short s; } u;
    u.h = __float2bfloat16(f);
    return u.s;
}

// Workspace layout (float offsets), ws_size ~256 MiB:
//  xT     [0, 2097152)             xT[(j*128+b)*8 + p]          8 MB fp32
//  blogT  [2097152, 6291456)       blogT[(n*J+j)*128 + b]     16 MB bf16
//  cT     [6291456, 10485760)      cT[(n*J+j)*128 + b]        16 MB bf16
//  s_part [10485760, 14680064)     [jc][b*512+n*16+d] x64     16 MB fp32
//  oT     [14680064, 14712832)     oT[(n*128+b)*16 + d]      128 KB bf16
//  Wbf    [14712832, 18907136)     W bf16, layout [n][j][d][p] 16 MB
//  Wt     [18907136, 23101440)     W bf16, layout [n][j][p][d] 16 MB
// total 92 MB

// ---------------------------------------------------------------------------
// P (merged prep): blocks [0,4096) = W fp32 -> Wbf/Wt bf16; blocks
// [4096,4352) = x -> xT transpose. Block-uniform branch, shared LDS union.
// ---------------------------------------------------------------------------
__global__ __launch_bounds__(256) void capsP(const float* __restrict__ W,
                                             __hip_bfloat16* __restrict__ Wbf,
                                             __hip_bfloat16* __restrict__ Wt,
                                             const float* __restrict__ x,
                                             float* __restrict__ xT) {
    __shared__ float lds[32 * 260 + 4];
    const int t = threadIdx.x;

    if (blockIdx.x < 4096) {
        const size_t base = (size_t)blockIdx.x * 2048;   // 16 rows x 128 elems
        const int r  = t >> 4;                           // row 0..15
        const int e0 = (t & 15) * 8;                     // elem offset in row

        float4 a = *(const float4*)(W + base + t * 8);
        float4 b = *(const float4*)(W + base + t * 8 + 4);
        short8b w8;
        w8[0]=bf16s(a.x); w8[1]=bf16s(a.y); w8[2]=bf16s(a.z); w8[3]=bf16s(a.w);
        w8[4]=bf16s(b.x); w8[5]=bf16s(b.y); w8[6]=bf16s(b.z); w8[7]=bf16s(b.w);
        *(short8b*)((short*)Wbf + base + t * 8) = w8;
        *(float4*)&lds[r * 132 + e0]     = a;
        *(float4*)&lds[r * 132 + e0 + 4] = b;
        __syncthreads();

        short8b o8;
        #pragma unroll
        for (int k = 0; k < 8; ++k) {
            int q = e0 + k;                 // Wt within-row index = p*16 + d
            int p = q >> 4, d = q & 15;
            o8[k] = bf16s(lds[r * 132 + d * 8 + p]);
        }
        *(short8b*)((short*)Wt + base + t * 8) = o8;
    } else {
        const int bid = blockIdx.x - 4096;
        const int jt = bid & 63;
        const int bt = bid >> 6;
        const int j0 = jt * 32, b0 = bt * 32;

        for (int idx = t; idx < 2048; idx += 256) {
            int bl = idx >> 6, f4 = idx & 63;
            float4 v = *(const float4*)(x + (size_t)(b0 + bl) * 16384 + j0 * 8 + f4 * 4);
            *(float4*)&lds[bl * 260 + f4 * 4] = v;
        }
        __syncthreads();
        for (int idx = t; idx < 2048; idx += 256) {
            int jj = idx >> 6, f4o = idx & 63;
            int bl = f4o >> 1, po = (f4o & 1) * 4;
            float4 v = *(const float4*)&lds[bl * 260 + jj * 8 + po];
            *(float4*)(xT + ((size_t)(j0 + jj) * 128 + b0 + bl) * 8 + po) = v;
        }
    }
}

// ---------------------------------------------------------------------------
// A (MFMA v5): block = (jc of 32 j, 4 n). x loaded ONCE per ks and reused
//   across 4 n (xT L2 traffic /4 — capsA was L2-BW bound). Grid 512 =
//   64 jc x 8 ng; same-jc blocks colocated per XCD. acc[4n][2tiles] f32x4,
//   all loops unrolled (static indices). Different ng -> disjoint n-slices
//   of s_part[jc]; verified r6 fragment/D layouts unchanged.
// ---------------------------------------------------------------------------
__global__ __launch_bounds__(256) void capsA(const __hip_bfloat16* __restrict__ Wbf,
                                             const float* __restrict__ xT,
                                             const __hip_bfloat16* __restrict__ cT,
                                             float* __restrict__ s_part,
                                             int mode) {
    const int t     = threadIdx.x;
    const int lane  = t & 63;
    const int i     = blockIdx.x;                    // 0..511
    const int xcd   = i & 7;
    const int r     = i >> 3;                        // 0..63
    const int jc    = xcd * 8 + (r & 7);             // 0..63 (XCD-grouped)
    const int ng    = r >> 3;                        // 0..7
    const int n0    = ng * 4;
    const int wv    = t >> 6;                        // 0..3
    const int colid = lane & 15;                     // d for B / b_low for A
    const int kgrp  = lane >> 4;                     // 0..3 -> j within K-step

    const int b0 = wv * 32 + colid;                  // A row, tile 0
    const int b1 = b0 + 16;                          // A row, tile 1

    f32x4 acc[4][2];
    #pragma unroll
    for (int nn = 0; nn < 4; ++nn) {
        acc[nn][0] = (f32x4){0.f, 0.f, 0.f, 0.f};
        acc[nn][1] = (f32x4){0.f, 0.f, 0.f, 0.f};
    }

    #pragma unroll
    for (int ks = 0; ks < 8; ++ks) {
        const int j = jc * 32 + ks * 4 + kgrp;       // per-lane j

        // ---- x loaded once, reused for all 4 n ----
        const float4* xp0 = (const float4*)(xT + ((size_t)j * 128 + b0) * 8);
        float4 xa = xp0[0], xb = xp0[1];
        const float4* xp1 = (const float4*)(xT + ((size_t)j * 128 + b1) * 8);
        float4 xe = xp1[0], xf = xp1[1];

        #pragma unroll
        for (int nn = 0; nn < 4; ++nn) {
            const int n = n0 + nn;

            short8b bfrag = *(const short8b*)((const short*)Wbf
                              + (((size_t)n * J_ + j) * 16 + colid) * 8);

            float c0 = 1.0f / 32.0f, c1 = 1.0f / 32.0f;
            if (mode) {
                c0 = __bfloat162float(cT[((size_t)n * J_ + j) * B_ + b0]);
                c1 = __bfloat162float(cT[((size_t)n * J_ + j) * B_ + b1]);
            }

            short8b afrag0;
            afrag0[0] = bf16s(xa.x * c0); afrag0[1] = bf16s(xa.y * c0);
            afrag0[2] = bf16s(xa.z * c0); afrag0[3] = bf16s(xa.w * c0);
            afrag0[4] = bf16s(xb.x * c0); afrag0[5] = bf16s(xb.y * c0);
            afrag0[6] = bf16s(xb.z * c0); afrag0[7] = bf16s(xb.w * c0);

            short8b afrag1;
            afrag1[0] = bf16s(xe.x * c1); afrag1[1] = bf16s(xe.y * c1);
            afrag1[2] = bf16s(xe.z * c1); afrag1[3] = bf16s(xe.w * c1);
            afrag1[4] = bf16s(xf.x * c1); afrag1[5] = bf16s(xf.y * c1);
            afrag1[6] = bf16s(xf.z * c1); afrag1[7] = bf16s(xf.w * c1);

            acc[nn][0] = __builtin_amdgcn_mfma_f32_16x16x32_bf16(afrag0, bfrag, acc[nn][0], 0, 0, 0);
            acc[nn][1] = __builtin_amdgcn_mfma_f32_16x16x32_bf16(afrag1, bfrag, acc[nn][1], 0, 0, 0);
        }
    }

    float* sdst = s_part + (size_t)jc * (B_ * N_ * D_);
    #pragma unroll
    for (int nn = 0; nn < 4; ++nn) {
        #pragma unroll
        for (int rr = 0; rr < 4; ++rr) {
            int brow = wv * 32 + kgrp * 4 + rr;
            sdst[(size_t)brow * 512 + (n0 + nn) * 16 + colid]        = acc[nn][0][rr];
            sdst[(size_t)(brow + 16) * 512 + (n0 + nn) * 16 + colid] = acc[nn][1][rr];
        }
    }
}

// ---------------------------------------------------------------------------
// R: out[b,n,d] = squash(sum_jc s_part + bias); also emit oT bf16 for capsB
// ---------------------------------------------------------------------------
__global__ __launch_bounds__(256) void capsR(const float* __restrict__ s_part,
                                             const float* __restrict__ bias,
                                             float* __restrict__ out,
                                             __hip_bfloat16* __restrict__ oT) {
    int gid = blockIdx.x * 256 + threadIdx.x;       // 65536: b*512 + n*16 + d
    float sv = bias[gid & 511];
    #pragma unroll
    for (int jc = 0; jc < NJC; ++jc)
        sv += s_part[(size_t)jc * 65536 + gid];
    float sq = sv * sv;
    sq += __shfl_xor(sq, 1);
    sq += __shfl_xor(sq, 2);
    sq += __shfl_xor(sq, 4);
    sq += __shfl_xor(sq, 8);
    float scale = sq / (1.0f + sq) / sqrtf(sq + 1e-7f);
    float ov = scale * sv;
    out[gid] = ov;
    int b = gid >> 9, nd = gid & 511;
    int n = nd >> 4, d = nd & 15;
    oT[((size_t)n * B_ + b) * D_ + d] = __float2bfloat16(ov);
}

// ---------------------------------------------------------------------------
// B (MFMA v9, round-16 exact): A-row remap (no shfl), 4-deep prefetch,
//   race-free per-lane (n,j,b) ownership.
// ---------------------------------------------------------------------------
__global__ __launch_bounds__(256) void capsB(const __hip_bfloat16* __restrict__ Wt,
                                             const float* __restrict__ xT,
                                             const __hip_bfloat16* __restrict__ oT,
                                             __hip_bfloat16* __restrict__ blogT,
                                             int accumulate) {
    const int t    = threadIdx.x;
    const int lane = t & 63;
    const int i    = blockIdx.x;              // 0..1023
    const int xcd  = i & 7;
    const int r    = i >> 3;                  // 0..127
    const int jq   = xcd * 64 + (r & 63);     // 0..511 (XCD owns 256 j)
    const int nh   = r >> 6;                  // 0..1
    const int j0   = jq * 4;
    const int wv   = t >> 6;                  // 0..3  -> owned b-tile
    const int g    = lane >> 5;               // lane half
    const int col  = lane & 31;
    const int b    = wv * 32 + col;           // wave-owned b (race-free)

    const int jlA = (col >> 4) + 2 * ((col >> 2) & 1);
    const int pA  = 4 * ((col >> 3) & 1) + (col & 3);

    float4 xv[4];
    #pragma unroll
    for (int jloc = 0; jloc < 2; ++jloc)
        #pragma unroll
        for (int h = 0; h < 2; ++h)
            xv[jloc * 2 + h] = *(const float4*)(xT
                + ((size_t)(j0 + 2 * g + jloc) * 128 + b) * 8 + h * 4);

    const short* wtBase = (const short*)Wt
        + (((size_t)(nh * 16) * J_ + j0 + jlA) * 8 + pA) * 16 + g * 8;
    const short* oBase  = (const short*)oT
        + ((size_t)(nh * 16) * B_ + b) * 16 + g * 8;
    const __hip_bfloat16* blogBase0 = blogT
        + ((size_t)(nh * 16) * J_ + j0 + 2 * g) * B_ + b;
    const __hip_bfloat16* blogBase1 = blogBase0 + B_;

    f32x16 zz;
    #pragma unroll
    for (int q = 0; q < 16; ++q) zz[q] = 0.0f;

    short8b af[4], bf[4];
    float   od0[4], od1[4];
    #pragma unroll
    for (int k = 0; k < 4; ++k) {
        af[k] = *(const short8b*)(wtBase + (size_t)k * (J_ * 128));
        bf[k] = *(const short8b*)(oBase  + (size_t)k * (B_ * 16));
        if (accumulate) {
            od0[k] = __bfloat162float(blogBase0[(size_t)k * (J_ * B_)]);
            od1[k] = __bfloat162float(blogBase1[(size_t)k * (J_ * B_)]);
        }
    }

    #pragma unroll
    for (int nn = 0; nn < 16; ++nn) {
        const int n = nh * 16 + nn;
        short8b afrag = af[nn & 3];
        short8b bfrag = bf[nn & 3];
        float old0 = od0[nn & 3], old1 = od1[nn & 3];
        if (nn + 4 < 16) {
            af[nn & 3] = *(const short8b*)(wtBase + (size_t)(nn + 4) * (J_ * 128));
            bf[nn & 3] = *(const short8b*)(oBase  + (size_t)(nn + 4) * (B_ * 16));
            if (accumulate) {
                od0[nn & 3] = __bfloat162float(blogBase0[(size_t)(nn + 4) * (J_ * B_)]);
                od1[nn & 3] = __bfloat162float(blogBase1[(size_t)(nn + 4) * (J_ * B_)]);
            }
        }

        f32x16 acc =
            __builtin_amdgcn_mfma_f32_32x32x16_bf16(afrag, bfrag, zz, 0, 0, 0);

        float t0 = acc[0] * xv[0].x + acc[1] * xv[0].y
                 + acc[2] * xv[0].z + acc[3] * xv[0].w
                 + acc[4] * xv[1].x + acc[5] * xv[1].y
                 + acc[6] * xv[1].z + acc[7] * xv[1].w;
        float t1 = acc[8]  * xv[2].x + acc[9]  * xv[2].y
                 + acc[10] * xv[2].z + acc[11] * xv[2].w
                 + acc[12] * xv[3].x + acc[13] * xv[3].y
                 + acc[14] * xv[3].z + acc[15] * xv[3].w;
        if (accumulate) { t0 += old0; t1 += old1; }

        size_t a0 = ((size_t)n * J_ + j0 + 2 * g) * B_ + b;
        blogT[a0]      = __float2bfloat16(t0);
        blogT[a0 + B_] = __float2bfloat16(t1);
    }
}

// ---------------------------------------------------------------------------
// D: per (j,b): softmax over n of blogT -> cT bf16 (consumed by capsA)
// ---------------------------------------------------------------------------
__global__ __launch_bounds__(256) void capsD(const __hip_bfloat16* __restrict__ blogT,
                                             __hip_bfloat16* __restrict__ cT) {
    int gid = blockIdx.x * 256 + threadIdx.x;   // 262144 = J_*B_ (j*128+b)
    float v[32];
    float m = -1e30f;
    #pragma unroll
    for (int nn = 0; nn < 32; ++nn) {
        v[nn] = __bfloat162float(blogT[(size_t)nn * (J_ * B_) + gid]);
        m = fmaxf(m, v[nn]);
    }
    float sum = 0.0f;
    #pragma unroll
    for (int nn = 0; nn < 32; ++nn) sum += __expf(v[nn] - m);
    float inv = 1.0f / sum;
    #pragma unroll
    for (int nn = 0; nn < 32; ++nn)
        cT[(size_t)nn * (J_ * B_) + gid] = __float2bfloat16(__expf(v[nn] - m) * inv);
}

// ---------------------------------------------------------------------------
extern "C" void kernel_launch(void* const* d_in, const int* in_sizes, int n_in,
                              void* d_out, int out_size, void* d_ws, size_t ws_size,
                              hipStream_t stream) {
    const float* x    = (const float*)d_in[0];   // [128,2048,8]
    const float* W    = (const float*)d_in[1];   // [32,2048,16,8]
    const float* bias = (const float*)d_in[2];   // [32,16]
    float* out = (float*)d_out;                  // [128,32,16]

    float* ws = (float*)d_ws;
    float*           xT     = ws;                                    // 8 MB
    __hip_bfloat16*  blogT  = (__hip_bfloat16*)(ws + 2097152);       // 16 MB
    __hip_bfloat16*  cT     = (__hip_bfloat16*)(ws + 6291456);       // 16 MB
    float*           s_part = ws + 10485760;                         // 16 MB
    __hip_bfloat16*  oT     = (__hip_bfloat16*)(ws + 14680064);      // 128 KB
    __hip_bfloat16*  Wbf    = (__hip_bfloat16*)(ws + 14712832);      // 16 MB
    __hip_bfloat16*  Wt     = (__hip_bfloat16*)(ws + 18907136);      // 16 MB

    dim3 b256(256);

    capsP<<<dim3(4352), b256, 0, stream>>>(W, Wbf, Wt, x, xT);

    // ---- routing iteration 0 (c uniform) ----
    capsA<<<dim3(512),  b256, 0, stream>>>(Wbf, xT, cT, s_part, 0);
    capsR<<<dim3(256),  b256, 0, stream>>>(s_part, bias, out, oT);
    capsB<<<dim3(1024), b256, 0, stream>>>(Wt, xT, oT, blogT, 0);

    // ---- routing iteration 1 ----
    capsD<<<dim3(1024), b256, 0, stream>>>(blogT, cT);
    capsA<<<dim3(512),  b256, 0, stream>>>(Wbf, xT, cT, s_part, 1);
    capsR<<<dim3(256),  b256, 0, stream>>>(s_part, bias, out, oT);
    capsB<<<dim3(1024), b256, 0, stream>>>(Wt, xT, oT, blogT, 1);

    // ---- routing iteration 2 (final) ----
    capsD<<<dim3(1024), b256, 0, stream>>>(blogT, cT);
    capsA<<<dim3(512),  b256, 0, stream>>>(Wbf, xT, cT, s_part, 1);
    capsR<<<dim3(256),  b256, 0, stream>>>(s_part, bias, out, oT);
}

// Round 19
// 121.110 us; speedup vs baseline: 1.2812x; 1.2812x over previous
//
#include <hip/hip_runtime.h>
#include <hip/hip_bf16.h>

// Problem constants
#define B_   128
#define J_   2048
#define N_   32
#define D_   16
#define NJC  32       // j-chunks (64 j each) for capsA s-partials

typedef __attribute__((ext_vector_type(8))) short short8b;   // 8 bf16 (4 VGPRs)
typedef __attribute__((ext_vector_type(4))) float f32x4;     // 16x16 MFMA acc
typedef __attribute__((ext_vector_type(16))) float f32x16;   // 32x32 MFMA acc

__device__ inline short bf16s(float f) {
    union { __hip_bfloat16 h; short s; } u;
    u.h = __float2bfloat16(f);
    return u.s;
}

// Workspace layout (float offsets), ws_size ~256 MiB:
//  xT     [0, 2097152)             xT[(j*128+b)*8 + p]          8 MB fp32
//  blogT  [2097152, 6291456)       blogT[(n*J+j)*128 + b]     16 MB bf16
//  cT     [6291456, 10485760)      cT[(n*J+j)*128 + b]        16 MB bf16
//  s_part [10485760, 12582912)     [jc][b*512+n*16+d]          8 MB fp32
//  oT     [12582912, 12615680)     oT[(n*128+b)*16 + d]      128 KB bf16
//  Wbf    [12615680, 16809984)     W bf16, layout [n][j][d][p] 16 MB
//  Wt     [16809984, 21004288)     W bf16, layout [n][j][p][d] 16 MB
// total 84 MB

// ---------------------------------------------------------------------------
// W: one-time W fp32 -> bf16 in two layouts (Wbf straight, Wt d<->p transposed)
// ---------------------------------------------------------------------------
__global__ __launch_bounds__(256) void capsW(const float* __restrict__ W,
                                             __hip_bfloat16* __restrict__ Wbf,
                                             __hip_bfloat16* __restrict__ Wt) {
    __shared__ float lds[16 * 132];
    const int t = threadIdx.x;
    const size_t base = (size_t)blockIdx.x * 2048;   // 16 rows x 128 elems
    const int r  = t >> 4;                           // row 0..15
    const int e0 = (t & 15) * 8;                     // elem offset within row

    float4 a = *(const float4*)(W + base + t * 8);
    float4 b = *(const float4*)(W + base + t * 8 + 4);
    short8b w8;
    w8[0]=bf16s(a.x); w8[1]=bf16s(a.y); w8[2]=bf16s(a.z); w8[3]=bf16s(a.w);
    w8[4]=bf16s(b.x); w8[5]=bf16s(b.y); w8[6]=bf16s(b.z); w8[7]=bf16s(b.w);
    *(short8b*)((short*)Wbf + base + t * 8) = w8;
    *(float4*)&lds[r * 132 + e0]     = a;
    *(float4*)&lds[r * 132 + e0 + 4] = b;
    __syncthreads();

    short8b o8;
    #pragma unroll
    for (int k = 0; k < 8; ++k) {
        int q = e0 + k;                 // Wt within-row index = p*16 + d
        int p = q >> 4, d = q & 15;
        o8[k] = bf16s(lds[r * 132 + d * 8 + p]);
    }
    *(short8b*)((short*)Wt + base + t * 8) = o8;
}

// ---------------------------------------------------------------------------
// T: xT[(j*128+b)*8+p] = x[b][j][p]   (LDS tile transpose)
// ---------------------------------------------------------------------------
__global__ __launch_bounds__(256) void capsT(const float* __restrict__ x,
                                             float* __restrict__ xT) {
    __shared__ float tile[32 * 260 + 4];
    const int t  = threadIdx.x;
    const int jt = blockIdx.x & 63;
    const int bt = blockIdx.x >> 6;
    const int j0 = jt * 32, b0 = bt * 32;

    for (int idx = t; idx < 2048; idx += 256) {
        int bl = idx >> 6, f4 = idx & 63;
        float4 v = *(const float4*)(x + (size_t)(b0 + bl) * 16384 + j0 * 8 + f4 * 4);
        *(float4*)&tile[bl * 260 + f4 * 4] = v;
    }
    __syncthreads();
    for (int idx = t; idx < 2048; idx += 256) {
        int jj = idx >> 6, f4o = idx & 63;
        int bl = f4o >> 1, po = (f4o & 1) * 4;
        float4 v = *(const float4*)&tile[bl * 260 + jj * 8 + po];
        *(float4*)(xT + ((size_t)(j0 + jj) * 128 + b0 + bl) * 8 + po) = v;
    }
}

// ---------------------------------------------------------------------------
// A (MFMA, round-12 exact): s_part[jc][b,n,d] = y(b,K) x W(K,d)
// ---------------------------------------------------------------------------
__global__ __launch_bounds__(256) void capsA(const __hip_bfloat16* __restrict__ Wbf,
                                             const float* __restrict__ xT,
                                             const __hip_bfloat16* __restrict__ cT,
                                             float* __restrict__ s_part,
                                             int mode) {
    const int t     = threadIdx.x;
    const int lane  = t & 63;
    const int i     = blockIdx.x;                    // 0..1023
    const int jc    = (i & 7) + 8 * (i >> 8);        // 0..31 (XCD-grouped)
    const int n     = (i >> 3) & 31;
    const int wv    = t >> 6;                        // 0..3
    const int colid = lane & 15;                     // d for B / b_low for A
    const int kgrp  = lane >> 4;                     // 0..3 -> j within K-step

    const int b0 = wv * 32 + colid;                  // A row, tile 0
    const int b1 = b0 + 16;                          // A row, tile 1

    f32x4 acc0 = {0.f, 0.f, 0.f, 0.f};
    f32x4 acc1 = {0.f, 0.f, 0.f, 0.f};

    for (int ks = 0; ks < 16; ++ks) {
        const int j = jc * 64 + ks * 4 + kgrp;       // per-lane j

        short8b bfrag = *(const short8b*)((const short*)Wbf
                          + (((size_t)n * J_ + j) * 16 + colid) * 8);

        float c0 = 1.0f / 32.0f, c1 = 1.0f / 32.0f;
        if (mode) {
            c0 = __bfloat162float(cT[((size_t)n * J_ + j) * B_ + b0]);
            c1 = __bfloat162float(cT[((size_t)n * J_ + j) * B_ + b1]);
        }

        const float4* xp0 = (const float4*)(xT + ((size_t)j * 128 + b0) * 8);
        float4 xa = xp0[0], xb = xp0[1];
        short8b afrag0;
        afrag0[0] = bf16s(xa.x * c0); afrag0[1] = bf16s(xa.y * c0);
        afrag0[2] = bf16s(xa.z * c0); afrag0[3] = bf16s(xa.w * c0);
        afrag0[4] = bf16s(xb.x * c0); afrag0[5] = bf16s(xb.y * c0);
        afrag0[6] = bf16s(xb.z * c0); afrag0[7] = bf16s(xb.w * c0);

        const float4* xp1 = (const float4*)(xT + ((size_t)j * 128 + b1) * 8);
        float4 xe = xp1[0], xf = xp1[1];
        short8b afrag1;
        afrag1[0] = bf16s(xe.x * c1); afrag1[1] = bf16s(xe.y * c1);
        afrag1[2] = bf16s(xe.z * c1); afrag1[3] = bf16s(xe.w * c1);
        afrag1[4] = bf16s(xf.x * c1); afrag1[5] = bf16s(xf.y * c1);
        afrag1[6] = bf16s(xf.z * c1); afrag1[7] = bf16s(xf.w * c1);

        acc0 = __builtin_amdgcn_mfma_f32_16x16x32_bf16(afrag0, bfrag, acc0, 0, 0, 0);
        acc1 = __builtin_amdgcn_mfma_f32_16x16x32_bf16(afrag1, bfrag, acc1, 0, 0, 0);
    }

    float* sdst = s_part + (size_t)jc * (B_ * N_ * D_);
    #pragma unroll
    for (int r = 0; r < 4; ++r) {
        int brow = wv * 32 + kgrp * 4 + r;
        sdst[(size_t)brow * 512 + n * 16 + colid]        = acc0[r];
        sdst[(size_t)(brow + 16) * 512 + n * 16 + colid] = acc1[r];
    }
}

// ---------------------------------------------------------------------------
// R: out[b,n,d] = squash(sum_jc s_part + bias); also emit oT bf16 for capsB
// ---------------------------------------------------------------------------
__global__ __launch_bounds__(256) void capsR(const float* __restrict__ s_part,
                                             const float* __restrict__ bias,
                                             float* __restrict__ out,
                                             __hip_bfloat16* __restrict__ oT) {
    int gid = blockIdx.x * 256 + threadIdx.x;       // 65536: b*512 + n*16 + d
    float sv = bias[gid & 511];
    #pragma unroll
    for (int jc = 0; jc < NJC; ++jc)
        sv += s_part[(size_t)jc * 65536 + gid];
    float sq = sv * sv;
    sq += __shfl_xor(sq, 1);
    sq += __shfl_xor(sq, 2);
    sq += __shfl_xor(sq, 4);
    sq += __shfl_xor(sq, 8);
    float scale = sq / (1.0f + sq) / sqrtf(sq + 1e-7f);
    float ov = scale * sv;
    out[gid] = ov;
    int b = gid >> 9, nd = gid & 511;
    int n = nd >> 4, d = nd & 15;
    oT[((size_t)n * B_ + b) * D_ + d] = __float2bfloat16(ov);
}

// ---------------------------------------------------------------------------
// B (MFMA v9): A-row REMAP kills the shfl. Row r ↔ (j,p) via
//   r = 8*(2*(j&1)+(p>>2)) + 4*(j>>1) + (p&3), so a lane's 16 D-regs hold
//   ALL 8 p for j in {2g, 2g+1}:  acc[8*jloc+q] == V[(j0+2g+jloc, p=q), b].
//   Epilogue: two 8-FMA dots + direct unguarded store (no shfl, no
//   divergence). 4-deep rotating prefetch for Wt/oT frags AND the
//   accumulate-mode blogT old values. Race-free per-lane (n,j,b) ownership.
// ---------------------------------------------------------------------------
__global__ __launch_bounds__(256) void capsB(const __hip_bfloat16* __restrict__ Wt,
                                             const float* __restrict__ xT,
                                             const __hip_bfloat16* __restrict__ oT,
                                             __hip_bfloat16* __restrict__ blogT,
                                             int accumulate) {
    const int t    = threadIdx.x;
    const int lane = t & 63;
    const int i    = blockIdx.x;              // 0..1023
    const int xcd  = i & 7;
    const int r    = i >> 3;                  // 0..127
    const int jq   = xcd * 64 + (r & 63);     // 0..511 (XCD owns 256 j)
    const int nh   = r >> 6;                  // 0..1
    const int j0   = jq * 4;
    const int wv   = t >> 6;                  // 0..3  -> owned b-tile
    const int g    = lane >> 5;               // lane half
    const int col  = lane & 31;
    const int b    = wv * 32 + col;           // wave-owned b (race-free)

    const int jlA = (col >> 4) + 2 * ((col >> 2) & 1);
    const int pA  = 4 * ((col >> 3) & 1) + (col & 3);

    float4 xv[4];
    #pragma unroll
    for (int jloc = 0; jloc < 2; ++jloc)
        #pragma unroll
        for (int h = 0; h < 2; ++h)
            xv[jloc * 2 + h] = *(const float4*)(xT
                + ((size_t)(j0 + 2 * g + jloc) * 128 + b) * 8 + h * 4);

    const short* wtBase = (const short*)Wt
        + (((size_t)(nh * 16) * J_ + j0 + jlA) * 8 + pA) * 16 + g * 8;
    const short* oBase  = (const short*)oT
        + ((size_t)(nh * 16) * B_ + b) * 16 + g * 8;
    const __hip_bfloat16* blogBase0 = blogT
        + ((size_t)(nh * 16) * J_ + j0 + 2 * g) * B_ + b;
    const __hip_bfloat16* blogBase1 = blogBase0 + B_;

    f32x16 zz;
    #pragma unroll
    for (int q = 0; q < 16; ++q) zz[q] = 0.0f;

    short8b af[4], bf[4];
    float   od0[4], od1[4];
    #pragma unroll
    for (int k = 0; k < 4; ++k) {
        af[k] = *(const short8b*)(wtBase + (size_t)k * (J_ * 128));
        bf[k] = *(const short8b*)(oBase  + (size_t)k * (B_ * 16));
        if (accumulate) {
            od0[k] = __bfloat162float(blogBase0[(size_t)k * (J_ * B_)]);
            od1[k] = __bfloat162float(blogBase1[(size_t)k * (J_ * B_)]);
        }
    }

    #pragma unroll
    for (int nn = 0; nn < 16; ++nn) {
        const int n = nh * 16 + nn;
        short8b afrag = af[nn & 3];
        short8b bfrag = bf[nn & 3];
        float old0 = od0[nn & 3], old1 = od1[nn & 3];
        if (nn + 4 < 16) {
            af[nn & 3] = *(const short8b*)(wtBase + (size_t)(nn + 4) * (J_ * 128));
            bf[nn & 3] = *(const short8b*)(oBase  + (size_t)(nn + 4) * (B_ * 16));
            if (accumulate) {
                od0[nn & 3] = __bfloat162float(blogBase0[(size_t)(nn + 4) * (J_ * B_)]);
                od1[nn & 3] = __bfloat162float(blogBase1[(size_t)(nn + 4) * (J_ * B_)]);
            }
        }

        f32x16 acc =
            __builtin_amdgcn_mfma_f32_32x32x16_bf16(afrag, bfrag, zz, 0, 0, 0);

        float t0 = acc[0] * xv[0].x + acc[1] * xv[0].y
                 + acc[2] * xv[0].z + acc[3] * xv[0].w
                 + acc[4] * xv[1].x + acc[5] * xv[1].y
                 + acc[6] * xv[1].z + acc[7] * xv[1].w;
        float t1 = acc[8]  * xv[2].x + acc[9]  * xv[2].y
                 + acc[10] * xv[2].z + acc[11] * xv[2].w
                 + acc[12] * xv[3].x + acc[13] * xv[3].y
                 + acc[14] * xv[3].z + acc[15] * xv[3].w;
        if (accumulate) { t0 += old0; t1 += old1; }

        size_t a0 = ((size_t)n * J_ + j0 + 2 * g) * B_ + b;
        blogT[a0]      = __float2bfloat16(t0);
        blogT[a0 + B_] = __float2bfloat16(t1);
    }
}

// ---------------------------------------------------------------------------
// D: per (j,b): softmax over n of blogT -> cT bf16 (consumed by capsA)
// ---------------------------------------------------------------------------
__global__ __launch_bounds__(256) void capsD(const __hip_bfloat16* __restrict__ blogT,
                                             __hip_bfloat16* __restrict__ cT) {
    int gid = blockIdx.x * 256 + threadIdx.x;   // 262144 = J_*B_ (j*128+b)
    float v[32];
    float m = -1e30f;
    #pragma unroll
    for (int nn = 0; nn < 32; ++nn) {
        v[nn] = __bfloat162float(blogT[(size_t)nn * (J_ * B_) + gid]);
        m = fmaxf(m, v[nn]);
    }
    float sum = 0.0f;
    #pragma unroll
    for (int nn = 0; nn < 32; ++nn) sum += __expf(v[nn] - m);
    float inv = 1.0f / sum;
    #pragma unroll
    for (int nn = 0; nn < 32; ++nn)
        cT[(size_t)nn * (J_ * B_) + gid] = __float2bfloat16(__expf(v[nn] - m) * inv);
}

// ---------------------------------------------------------------------------
extern "C" void kernel_launch(void* const* d_in, const int* in_sizes, int n_in,
                              void* d_out, int out_size, void* d_ws, size_t ws_size,
                              hipStream_t stream) {
    const float* x    = (const float*)d_in[0];   // [128,2048,8]
    const float* W    = (const float*)d_in[1];   // [32,2048,16,8]
    const float* bias = (const float*)d_in[2];   // [32,16]
    float* out = (float*)d_out;                  // [128,32,16]

    float* ws = (float*)d_ws;
    float*           xT     = ws;                                    // 8 MB
    __hip_bfloat16*  blogT  = (__hip_bfloat16*)(ws + 2097152);       // 16 MB
    __hip_bfloat16*  cT     = (__hip_bfloat16*)(ws + 6291456);       // 16 MB
    float*           s_part = ws + 10485760;                         // 8 MB
    __hip_bfloat16*  oT     = (__hip_bfloat16*)(ws + 12582912);      // 128 KB
    __hip_bfloat16*  Wbf    = (__hip_bfloat16*)(ws + 12615680);      // 16 MB
    __hip_bfloat16*  Wt     = (__hip_bfloat16*)(ws + 16809984);      // 16 MB

    dim3 b256(256);

    capsW<<<dim3(4096), b256, 0, stream>>>(W, Wbf, Wt);
    capsT<<<dim3(256),  b256, 0, stream>>>(x, xT);

    // ---- routing iteration 0 (c uniform) ----
    capsA<<<dim3(1024), b256, 0, stream>>>(Wbf, xT, cT, s_part, 0);
    capsR<<<dim3(256),  b256, 0, stream>>>(s_part, bias, out, oT);
    capsB<<<dim3(1024), b256, 0, stream>>>(Wt, xT, oT, blogT, 0);

    // ---- routing iteration 1 ----
    capsD<<<dim3(1024), b256, 0, stream>>>(blogT, cT);
    capsA<<<dim3(1024), b256, 0, stream>>>(Wbf, xT, cT, s_part, 1);
    capsR<<<dim3(256),  b256, 0, stream>>>(s_part, bias, out, oT);
    capsB<<<dim3(1024), b256, 0, stream>>>(Wt, xT, oT, blogT, 1);

    // ---- routing iteration 2 (final) ----
    capsD<<<dim3(1024), b256, 0, stream>>>(blogT, cT);
    capsA<<<dim3(1024), b256, 0, stream>>>(Wbf, xT, cT, s_part, 1);
    capsR<<<dim3(256),  b256, 0, stream>>>(s_part, bias, out, oT);
}